// Round 7
// baseline (245.021 us; speedup 1.0000x reference)
//
#include <hip/hip_runtime.h>
#include <hip/hip_bf16.h>

typedef __bf16 bf16_t;
typedef bf16_t bf16x4 __attribute__((ext_vector_type(4)));
typedef bf16_t bf16x8 __attribute__((ext_vector_type(8)));
typedef float floatx4 __attribute__((ext_vector_type(4)));

typedef __attribute__((address_space(1))) const unsigned char* gptr_t;
typedef __attribute__((address_space(3))) unsigned char* lptr_t;

#define BATCH 4
#define SEQ_N 2048
#define SEQ_M 2048
#define DIM 1024
#define INNER 512
#define HEADS 8
#define DHEAD 64
// 0.125 * log2(e): folded into Wq so attention scores arrive in exp2 domain
#define QSCALE 0.18033688011112042f

// Raw hardware exp2 via compiler-visible builtin (R4-verified: -20 µs, safe).
#if __has_builtin(__builtin_amdgcn_exp2f)
#define fast_exp2(x) __builtin_amdgcn_exp2f(x)
#else
#define fast_exp2(x) exp2f(x)
#endif

// ---------------- Prep: weight convert+transpose AND LayerNorm, one dispatch
__device__ __forceinline__ void wtrans_tile(const float* W, bf16_t* Wt,
                                            int K, int N, int n0, int k0, float scale) {
    __shared__ bf16_t T[64][72];
    const int tid = threadIdx.x;
#pragma unroll
    for (int p = 0; p < 2; p++) {
        int r = (tid >> 3) + p * 32;       // k
        int c = (tid & 7) * 8;             // n
        const float* src = W + (size_t)(k0 + r) * N + n0 + c;
        float4 v0 = *(const float4*)src;
        float4 v1 = *(const float4*)(src + 4);
        T[r][c + 0] = (bf16_t)(v0.x * scale); T[r][c + 1] = (bf16_t)(v0.y * scale);
        T[r][c + 2] = (bf16_t)(v0.z * scale); T[r][c + 3] = (bf16_t)(v0.w * scale);
        T[r][c + 4] = (bf16_t)(v1.x * scale); T[r][c + 5] = (bf16_t)(v1.y * scale);
        T[r][c + 6] = (bf16_t)(v1.z * scale); T[r][c + 7] = (bf16_t)(v1.w * scale);
    }
    __syncthreads();
#pragma unroll
    for (int p = 0; p < 2; p++) {
        int rn = (tid >> 3) + p * 32;      // n
        int ck = (tid & 7) * 8;            // k
        bf16x8 v;
#pragma unroll
        for (int i = 0; i < 8; i++) v[i] = T[ck + i][rn];
        *(bf16x8*)(Wt + (size_t)(n0 + rn) * K + k0 + ck) = v;
    }
}

// One LN row per wave: shuffle-only reduction, no barriers, no LDS.
__device__ __forceinline__ void ln_row_wave(const float* in, const float* g,
                                            const float* bt, bf16_t* out, int row) {
    const int lane = threadIdx.x & 63;
    const float4* src = (const float4*)(in + (size_t)row * 1024);
    float4 xv[4];
    float s = 0.f, ss = 0.f;
#pragma unroll
    for (int k = 0; k < 4; k++) {
        xv[k] = src[lane + k * 64];
        s  += xv[k].x + xv[k].y + xv[k].z + xv[k].w;
        ss += xv[k].x * xv[k].x + xv[k].y * xv[k].y + xv[k].z * xv[k].z + xv[k].w * xv[k].w;
    }
#pragma unroll
    for (int off = 32; off > 0; off >>= 1) {
        s  += __shfl_down(s, off);
        ss += __shfl_down(ss, off);
    }
    s  = __shfl(s, 0);
    ss = __shfl(ss, 0);
    const float mu = s * (1.f / 1024.f);
    const float var = ss * (1.f / 1024.f) - mu * mu;
    const float rs = rsqrtf(var + 1e-5f);
    const float4* gp = (const float4*)g;
    const float4* bp = (const float4*)bt;
#pragma unroll
    for (int k = 0; k < 4; k++) {
        float4 gv = gp[lane + k * 64], bv = bp[lane + k * 64];
        bf16x4 o;
        o[0] = (bf16_t)((xv[k].x - mu) * rs * gv.x + bv.x);
        o[1] = (bf16_t)((xv[k].y - mu) * rs * gv.y + bv.y);
        o[2] = (bf16_t)((xv[k].z - mu) * rs * gv.z + bv.z);
        o[3] = (bf16_t)((xv[k].w - mu) * rs * gv.w + bv.w);
        *(bf16x4*)(out + (size_t)row * 1024 + (lane + k * 64) * 4) = o;
    }
}

__global__ __launch_bounds__(256) void prep_kernel(const float* __restrict__ x,
                                                   const float* __restrict__ ctx,
                                                   const float* __restrict__ g1,
                                                   const float* __restrict__ b1,
                                                   const float* __restrict__ g2,
                                                   const float* __restrict__ b2,
                                                   const float* __restrict__ Wq,
                                                   const float* __restrict__ Wkv,
                                                   const float* __restrict__ Wout,
                                                   bf16_t* __restrict__ xn,
                                                   bf16_t* __restrict__ cn,
                                                   bf16_t* __restrict__ Wqt,
                                                   bf16_t* __restrict__ Wkvt,
                                                   bf16_t* __restrict__ Woutt) {
    int id = blockIdx.x;
    if (id < 128) {
        wtrans_tile(Wq, Wqt, 1024, 512, (id & 7) * 64, (id >> 3) * 64, QSCALE);
    } else if (id < 384) {
        int t = id - 128;
        wtrans_tile(Wkv, Wkvt, 1024, 1024, (t & 15) * 64, (t >> 4) * 64, 1.0f);
    } else if (id < 512) {
        int t = id - 384;
        wtrans_tile(Wout, Woutt, 512, 1024, (t & 15) * 64, (t >> 4) * 64, 1.0f);
    } else {
        int row = (id - 512) * 4 + (threadIdx.x >> 6);   // one row per wave
        if (row < BATCH * SEQ_N) ln_row_wave(x, g1, b1, xn, row);
        else                     ln_row_wave(ctx, g2, b2, cn, row - BATCH * SEQ_N);
    }
}

// ---------------- m97-style GEMM body; NT = col-tile width (128 or 64) ------
// MODE 0: C[row*ldC + col] (+bias). MODE 1 (NT=128): transposed output (V^T):
// operand-swapped MFMA -> D^T in regs -> per-wave LDS transpose -> vector stores.
template <int NT, int MODE, typename OutT>
__device__ __forceinline__ void gemm_body(const bf16_t* __restrict__ A,
                                          const bf16_t* __restrict__ Bt,
                                          OutT* __restrict__ C,
                                          const float* __restrict__ bias,
                                          int ldC, int K, int row0, int col0) {
    __shared__ bf16_t As[128 * 64];
    __shared__ bf16_t Bs[NT * 64];
    const int tid = threadIdx.x;
    const int wave = tid >> 6, lane = tid & 63;
    constexpr int WC = NT / 2;      // wave col extent
    constexpr int NJ = WC / 16;     // 4 or 2
    const int wr = (wave >> 1) * 64, wc = (wave & 1) * WC;
    const int quad = lane >> 4, l16 = lane & 15;

    floatx4 acc[4][NJ] = {};

    for (int k0 = 0; k0 < K; k0 += 64) {
#pragma unroll
        for (int p = 0; p < 4; p++) {
            int cA = p * 256 + wave * 64 + lane;
            int rA = cA >> 3, kc = (cA & 7) * 8;
            __builtin_amdgcn_global_load_lds(
                (gptr_t)(A + (size_t)(row0 + rA) * K + k0 + kc),
                (lptr_t)(As + (size_t)(p * 256 + wave * 64) * 8), 16, 0, 0);
            if (p < NT / 32)
                __builtin_amdgcn_global_load_lds(
                    (gptr_t)(Bt + (size_t)(col0 + rA) * K + k0 + kc),
                    (lptr_t)(Bs + (size_t)(p * 256 + wave * 64) * 8), 16, 0, 0);
        }
        __syncthreads();
#pragma unroll
        for (int kt = 0; kt < 2; kt++) {
            bf16x8 aF[4], bF[NJ];
#pragma unroll
            for (int i = 0; i < 4; i++)
                aF[i] = *(bf16x8*)&As[(wr + i * 16 + l16) * 64 + kt * 32 + quad * 8];
#pragma unroll
            for (int j = 0; j < NJ; j++)
                bF[j] = *(bf16x8*)&Bs[(wc + j * 16 + l16) * 64 + kt * 32 + quad * 8];
#pragma unroll
            for (int i = 0; i < 4; i++)
#pragma unroll
                for (int j = 0; j < NJ; j++) {
                    if (MODE == 0)
                        acc[i][j] = __builtin_amdgcn_mfma_f32_16x16x32_bf16(
                            aF[i], bF[j], acc[i][j], 0, 0, 0);
                    else  // transposed output: D^T
                        acc[i][j] = __builtin_amdgcn_mfma_f32_16x16x32_bf16(
                            bF[j], aF[i], acc[i][j], 0, 0, 0);
                }
        }
        __syncthreads();
    }

    if (MODE == 0) {
#pragma unroll
        for (int i = 0; i < 4; i++)
#pragma unroll
            for (int j = 0; j < NJ; j++) {
                int col = col0 + wc + j * 16 + l16;
                float bv = bias ? bias[col] : 0.f;
#pragma unroll
                for (int r = 0; r < 4; r++) {
                    int row = row0 + wr + i * 16 + quad * 4 + r;
                    C[(size_t)row * ldC + col] = (OutT)(acc[i][j][r] + bv);
                }
            }
    } else {
        // lane holds D^T[d_local = j*16+quad*4+r][m_local = i*16+l16] for wave
        // tile (64 m x 64 d). Transpose via per-wave LDS chunk, then vector-store.
        bf16_t* Tw = (wave < 2 ? As : Bs) + (wave & 1) * 4096;  // 64x64, stride 64
#pragma unroll
        for (int i = 0; i < 4; i++)
#pragma unroll
            for (int j = 0; j < 4; j++)
#pragma unroll
                for (int r = 0; r < 4; r++)
                    Tw[(j * 16 + quad * 4 + r) * 64 + i * 16 + l16] = (bf16_t)acc[i][j][r];
        __syncthreads();
        const int grow = row0 + wr;                  // wave m base (64 aligned)
        const int bat = grow >> 11, gm = (grow & 2047) + l16 * 4;
#pragma unroll
        for (int dd = 0; dd < 16; dd++) {
            int d = dd * 4 + quad;
            bf16x4 v = *(bf16x4*)&Tw[d * 64 + l16 * 4];
            int gd = col0 + wc + d - 512;
            *(bf16x4*)(C + ((size_t)bat * 512 + gd) * 2048 + gm) = v;
        }
    }
}

// Fused q/k/v projections, XCD-chunked 1D grid (768 blocks, 768%8==0):
// each XCD owns 8 consecutive 128-row panels (all 12 col-tiles) -> A-panels
// read once per XCD, weights (<=3MB) stay L2-resident.
__global__ __launch_bounds__(256) void gemm_qkv_kernel(const bf16_t* __restrict__ xn,
                                                       const bf16_t* __restrict__ cn,
                                                       const bf16_t* __restrict__ Wqt,
                                                       const bf16_t* __restrict__ Wkvt,
                                                       bf16_t* __restrict__ qb,
                                                       bf16_t* __restrict__ kvb,
                                                       bf16_t* __restrict__ Vtg) {
    const int f = blockIdx.x;
    const int lb = (f & 7) * 96 + (f >> 3);
    const int bx = lb % 12;
    const int row0 = (lb / 12) * 128;
    if (bx < 4)
        gemm_body<128, 0, bf16_t>(xn, Wqt, qb, nullptr, 512, DIM, row0, bx * 128);
    else if (bx < 8)
        gemm_body<128, 0, bf16_t>(cn, Wkvt, kvb, nullptr, 512, DIM, row0, (bx - 4) * 128);
    else
        gemm_body<128, 1, bf16_t>(cn, Wkvt, Vtg, nullptr, 0, DIM, row0, (bx - 4) * 128);
}

// XCD-chunked 1D grid (1024 blocks): each XCD owns 8 row-panels of ao.
__global__ __launch_bounds__(256) void gemm_out_kernel(const bf16_t* __restrict__ ao,
                                                       const bf16_t* __restrict__ Woutt,
                                                       float* __restrict__ out,
                                                       const float* __restrict__ bias) {
    const int f = blockIdx.x;
    const int lb = (f & 7) * 128 + (f >> 3);
    gemm_body<64, 0, float>(ao, Woutt, out, bias, DIM, INNER,
                            (lb >> 4) * 128, (lb & 15) * 64);
}

// ---------------- Flash attention v7 = v6 structure, K AND V staged by
// global_load_lds (pre-swizzled per-lane source, LINEAR LDS dest == XOR
// layout), double-buffered, issued one tile AHEAD right after the barrier.
// R5 proved: (a) the glds-K path with this schedule is correct & sufficient
// (in flight a full iteration >> L2 latency); (b) V must keep a cross-iter
// buffer (same-iter V loads stalled PV by the L2 round trip). v7 keeps the
// LDS dbuf for BOTH and deletes the reg round-trip: -8 ds_write_b128 and
// -8 global->reg loads per wave-iter, -64 VGPR of kreg/vreg, less VALU.
// q: [b,n,512]; kv: [b,m,512] K-only; Vtg: [(b*8+h)*64+d][m]. o: [b,n,512].
__global__ __launch_bounds__(128) void attn_kernel(const bf16_t* __restrict__ q,
                                                   const bf16_t* __restrict__ kv,
                                                   const bf16_t* __restrict__ Vtg,
                                                   bf16_t* __restrict__ o) {
    __shared__ bf16_t Qs[64 * 64];       // Q staging; later per-wave P buffers
    __shared__ bf16_t Ks[2][64 * 64];    // [krow][d] XOR layout, dbuf
    __shared__ bf16_t Vs[2][64 * 64];    // [d][krow] XOR layout, dbuf

    // XCD-chunked block swizzle: hw dispatch f -> xcd f&7 gets 128 consecutive
    // logical blocks = 4 (b,h) pairs (KV footprint ~2MB < 4MB per-XCD L2).
    const int f = blockIdx.x;
    const int lb = ((f & 7) << 7) | (f >> 3);
    const int b = lb >> 8, h = (lb >> 5) & 7;
    const int n0 = (lb & 31) * 64;

    const int tid = threadIdx.x;
    const int wave = tid >> 6, lane = tid & 63;
    const int quad = lane >> 4, l16 = lane & 15;
    const int swz = (l16 & 7) << 3;          // read-side XOR (row&7 == l16&7)

    const int sr = tid >> 3;                 // Q staging row base (0..15)
    const int sc = (tid & 7) * 8;            // Q staging col
    const int scs = sc ^ ((sr & 7) << 3);    // write-side XOR (row&7 == sr&7)

    // glds staging: lane covers row rloc=(lane>>3) of an 8-row chunk, 16B col
    // chunk (lane&7); source col pre-swizzled so linear LDS dest == XOR layout.
    // Per wave: chunks wave*4+p (p=0..3), rows wave*32+p*8+rloc, row&7 == rloc.
    const int rloc = lane >> 3;                        // 0..7
    const int srccol = ((lane & 7) ^ rloc) << 3;       // (a ^ r)*8 elems
    const bf16_t* kgl = kv + ((size_t)(b * SEQ_M) + wave * 32 + rloc) * 512
                           + h * DHEAD + srccol;
    const bf16_t* vgl = Vtg + ((size_t)((b * HEADS + h) * DHEAD)
                               + wave * 32 + rloc) * SEQ_M + srccol;

    // issue K/V tile 0 -> buf 0 (drained by the vmcnt(0) at the first barrier)
#pragma unroll
    for (int p = 0; p < 4; p++) {
        __builtin_amdgcn_global_load_lds(
            (gptr_t)(kgl + (size_t)(p * 8) * 512),
            (lptr_t)(Ks[0] + (wave * 4 + p) * 512), 16, 0, 0);
        __builtin_amdgcn_global_load_lds(
            (gptr_t)(vgl + (size_t)(p * 8) * SEQ_M),
            (lptr_t)(Vs[0] + (wave * 4 + p) * 512), 16, 0, 0);
    }

    // stage Q tile [64][64] (swizzled, reg path)
#pragma unroll
    for (int p = 0; p < 4; p++) {
        int r = sr + p * 16;
        *(bf16x8*)&Qs[r * 64 + scs] =
            *(const bf16x8*)(q + (size_t)(b * SEQ_N + n0 + r) * INNER + h * DHEAD + sc);
    }

    // ones B-frag for the l-column MFMA: B[k][n=l16] = (l16==0) ? 1 : 0
    bf16x8 bOnes;
    {
        bf16_t ov = (l16 == 0) ? (bf16_t)1.0f : (bf16_t)0.0f;
#pragma unroll
        for (int i = 0; i < 8; i++) bOnes[i] = ov;
    }

    __syncthreads();     // Q visible; K0/V0 drained

    // per-wave Q fragments: 2 sets of 16 q-rows (rows wave*32 .. wave*32+31)
    bf16x8 aQ0[2], aQ1[2];
#pragma unroll
    for (int kt = 0; kt < 2; kt++) {
        aQ0[kt] = *(bf16x8*)&Qs[(wave * 32 + l16) * 64 + ((kt * 32 + quad * 8) ^ swz)];
        aQ1[kt] = *(bf16x8*)&Qs[(wave * 32 + 16 + l16) * 64 + ((kt * 32 + quad * 8) ^ swz)];
    }

    // issue K/V tile 1 -> buf 1 (in flight during iter 0)
    kgl += (size_t)64 * 512;
    vgl += 64;
#pragma unroll
    for (int p = 0; p < 4; p++) {
        __builtin_amdgcn_global_load_lds(
            (gptr_t)(kgl + (size_t)(p * 8) * 512),
            (lptr_t)(Ks[1] + (wave * 4 + p) * 512), 16, 0, 0);
        __builtin_amdgcn_global_load_lds(
            (gptr_t)(vgl + (size_t)(p * 8) * SEQ_M),
            (lptr_t)(Vs[1] + (wave * 4 + p) * 512), 16, 0, 0);
    }

    // per-wave P buffers alias this wave's (already-consumed) Qs rows
    bf16_t* Pw0 = Qs + wave * 2048;          // set 0: rows wave*32..+15
    bf16_t* Pw1 = Pw0 + 1024;                // set 1: rows wave*32+16..+31

    floatx4 oacc0[5] = {}, oacc1[5] = {};    // [0..3]=O d-tiles, [4]=l (col 0)

    int cur = 0;
    for (int it = 0; it < SEQ_M / 64; ++it) {
        // S^T = K @ Q^T (exp2 domain): aK read once, feeds BOTH q-sets
        floatx4 s0[4] = {}, s1[4] = {};
        __builtin_amdgcn_s_setprio(1);
#pragma unroll
        for (int kt = 0; kt < 2; kt++)
#pragma unroll
            for (int jt = 0; jt < 4; jt++) {
                bf16x8 aK = *(bf16x8*)&Ks[cur][(jt * 16 + l16) * 64 +
                                              ((kt * 32 + quad * 8) ^ swz)];
                s0[jt] = __builtin_amdgcn_mfma_f32_16x16x32_bf16(aK, aQ0[kt], s0[jt], 0, 0, 0);
                s1[jt] = __builtin_amdgcn_mfma_f32_16x16x32_bf16(aK, aQ1[kt], s1[jt], 0, 0, 0);
            }
        __builtin_amdgcn_s_setprio(0);

        // P = exp2(S^T): packed b64 stores at P[q=l16][m=jt*16+quad*4]
#pragma unroll
        for (int jt = 0; jt < 4; jt++) {
            bf16x4 pk0, pk1;
#pragma unroll
            for (int r = 0; r < 4; r++) {
                pk0[r] = (bf16_t)fast_exp2(s0[jt][r]);
                pk1[r] = (bf16_t)fast_exp2(s1[jt][r]);
            }
            int pc = (jt * 16 + quad * 4) ^ swz;
            *(bf16x4*)&Pw0[l16 * 64 + pc] = pk0;
            *(bf16x4*)&Pw1[l16 * 64 + pc] = pk1;
        }

        // O += P @ V; bV read once, feeds BOTH q-sets; l via register ones-frag
        __builtin_amdgcn_s_setprio(1);
#pragma unroll
        for (int kt = 0; kt < 2; kt++) {
            int ac = (kt * 32 + quad * 8) ^ swz;
            bf16x8 aP0 = *(bf16x8*)&Pw0[l16 * 64 + ac];
            bf16x8 aP1 = *(bf16x8*)&Pw1[l16 * 64 + ac];
#pragma unroll
            for (int dt = 0; dt < 4; dt++) {
                bf16x8 bV = *(bf16x8*)&Vs[cur][(dt * 16 + l16) * 64 + ac];
                oacc0[dt] = __builtin_amdgcn_mfma_f32_16x16x32_bf16(aP0, bV, oacc0[dt], 0, 0, 0);
                oacc1[dt] = __builtin_amdgcn_mfma_f32_16x16x32_bf16(aP1, bV, oacc1[dt], 0, 0, 0);
            }
            oacc0[4] = __builtin_amdgcn_mfma_f32_16x16x32_bf16(aP0, bOnes, oacc0[4], 0, 0, 0);
            oacc1[4] = __builtin_amdgcn_mfma_f32_16x16x32_bf16(aP1, bOnes, oacc1[4], 0, 0, 0);
        }
        __builtin_amdgcn_s_setprio(0);

        __syncthreads();     // tile-it reads retired; K/V(it+1) glds drained

        // issue K/V(it+2) into the buffer just freed (in flight a full iter;
        // OOB tail reads land in owned ws regions, unused)
        kgl += (size_t)64 * 512;
        vgl += 64;
#pragma unroll
        for (int p = 0; p < 4; p++) {
            __builtin_amdgcn_global_load_lds(
                (gptr_t)(kgl + (size_t)(p * 8) * 512),
                (lptr_t)(Ks[cur] + (wave * 4 + p) * 512), 16, 0, 0);
            __builtin_amdgcn_global_load_lds(
                (gptr_t)(vgl + (size_t)(p * 8) * SEQ_M),
                (lptr_t)(Vs[cur] + (wave * 4 + p) * 512), 16, 0, 0);
        }
        cur ^= 1;
    }

    // epilogue: l in oacc*[4] col 0; broadcast within quad-row group
#pragma unroll
    for (int set = 0; set < 2; set++) {
        const floatx4* oa = set == 0 ? oacc0 : oacc1;   // compile-time select
        float inv[4];
#pragma unroll
        for (int r = 0; r < 4; r++) {
            float l = __shfl(oa[4][r], (int)(lane & 48));
            inv[r] = 1.0f / l;
        }
#pragma unroll
        for (int dt = 0; dt < 4; dt++)
#pragma unroll
            for (int r = 0; r < 4; r++) {
                int row = n0 + wave * 32 + set * 16 + quad * 4 + r;
                int col = h * DHEAD + dt * 16 + l16;
                o[(size_t)(b * SEQ_N + row) * INNER + col] =
                    (bf16_t)(oa[dt][r] * inv[r]);
            }
    }
}

extern "C" void kernel_launch(void* const* d_in, const int* in_sizes, int n_in,
                              void* d_out, int out_size, void* d_ws, size_t ws_size,
                              hipStream_t stream) {
    const float* x    = (const float*)d_in[0];
    const float* ctx  = (const float*)d_in[1];
    const float* g1   = (const float*)d_in[2];
    const float* b1   = (const float*)d_in[3];
    const float* g2   = (const float*)d_in[4];
    const float* b2   = (const float*)d_in[5];
    const float* Wq   = (const float*)d_in[6];
    const float* Wkv  = (const float*)d_in[7];
    const float* Wout = (const float*)d_in[8];
    const float* bout = (const float*)d_in[9];
    float* out = (float*)d_out;

    const int rows = BATCH * SEQ_N;  // 8192
    bf16_t* xn    = (bf16_t*)d_ws;                       // 8M elem; reused as attn out
    bf16_t* cn    = xn + (size_t)rows * DIM;             // 8M
    bf16_t* qb    = cn + (size_t)rows * DIM;             // 4M
    bf16_t* kvb   = qb + (size_t)rows * INNER;           // 4M (K only, stride 512)
    bf16_t* Vtg   = kvb + (size_t)rows * INNER;          // 4M (V transposed)
    bf16_t* Wqt   = Vtg + (size_t)rows * INNER;          // 0.5M
    bf16_t* Wkvt  = Wqt + (size_t)INNER * DIM;           // 1M
    bf16_t* Woutt = Wkvt + (size_t)(2 * INNER) * DIM;    // 0.5M
    bf16_t* o_attn = xn;  // alias: xn dead after qkv GEMM

    prep_kernel<<<512 + (2 * rows) / 4, 256, 0, stream>>>(
        x, ctx, g1, b1, g2, b2, Wq, Wkv, Wout, xn, cn, Wqt, Wkvt, Woutt);
    gemm_qkv_kernel<<<768, 256, 0, stream>>>(
        xn, cn, Wqt, Wkvt, qb, kvb, Vtg);
    attn_kernel<<<1024, 128, 0, stream>>>(qb, kvb, Vtg, o_attn);
    gemm_out_kernel<<<1024, 256, 0, stream>>>(o_attn, Woutt, out, bout);
}

// Round 8
// 239.431 us; speedup vs baseline: 1.0233x; 1.0233x over previous
//
#include <hip/hip_runtime.h>
#include <hip/hip_bf16.h>

typedef __bf16 bf16_t;
typedef bf16_t bf16x4 __attribute__((ext_vector_type(4)));
typedef bf16_t bf16x8 __attribute__((ext_vector_type(8)));
typedef float floatx4 __attribute__((ext_vector_type(4)));

typedef __attribute__((address_space(1))) const unsigned char* gptr_t;
typedef __attribute__((address_space(3))) unsigned char* lptr_t;

#define BATCH 4
#define SEQ_N 2048
#define SEQ_M 2048
#define DIM 1024
#define INNER 512
#define HEADS 8
#define DHEAD 64
// 0.125 * log2(e): folded into Wq so attention scores arrive in exp2 domain
#define QSCALE 0.18033688011112042f

// Raw hardware exp2 via compiler-visible builtin (R4-verified: -20 µs, safe).
#if __has_builtin(__builtin_amdgcn_exp2f)
#define fast_exp2(x) __builtin_amdgcn_exp2f(x)
#else
#define fast_exp2(x) exp2f(x)
#endif

// ---------------- Prep: weight convert+transpose AND LayerNorm, one dispatch
__device__ __forceinline__ void wtrans_tile(const float* W, bf16_t* Wt,
                                            int K, int N, int n0, int k0, float scale) {
    __shared__ bf16_t T[64][72];
    const int tid = threadIdx.x;
#pragma unroll
    for (int p = 0; p < 2; p++) {
        int r = (tid >> 3) + p * 32;       // k
        int c = (tid & 7) * 8;             // n
        const float* src = W + (size_t)(k0 + r) * N + n0 + c;
        float4 v0 = *(const float4*)src;
        float4 v1 = *(const float4*)(src + 4);
        T[r][c + 0] = (bf16_t)(v0.x * scale); T[r][c + 1] = (bf16_t)(v0.y * scale);
        T[r][c + 2] = (bf16_t)(v0.z * scale); T[r][c + 3] = (bf16_t)(v0.w * scale);
        T[r][c + 4] = (bf16_t)(v1.x * scale); T[r][c + 5] = (bf16_t)(v1.y * scale);
        T[r][c + 6] = (bf16_t)(v1.z * scale); T[r][c + 7] = (bf16_t)(v1.w * scale);
    }
    __syncthreads();
#pragma unroll
    for (int p = 0; p < 2; p++) {
        int rn = (tid >> 3) + p * 32;      // n
        int ck = (tid & 7) * 8;            // k
        bf16x8 v;
#pragma unroll
        for (int i = 0; i < 8; i++) v[i] = T[ck + i][rn];
        *(bf16x8*)(Wt + (size_t)(n0 + rn) * K + k0 + ck) = v;
    }
}

// One LN row per wave: shuffle-only reduction, no barriers, no LDS.
__device__ __forceinline__ void ln_row_wave(const float* in, const float* g,
                                            const float* bt, bf16_t* out, int row) {
    const int lane = threadIdx.x & 63;
    const float4* src = (const float4*)(in + (size_t)row * 1024);
    float4 xv[4];
    float s = 0.f, ss = 0.f;
#pragma unroll
    for (int k = 0; k < 4; k++) {
        xv[k] = src[lane + k * 64];
        s  += xv[k].x + xv[k].y + xv[k].z + xv[k].w;
        ss += xv[k].x * xv[k].x + xv[k].y * xv[k].y + xv[k].z * xv[k].z + xv[k].w * xv[k].w;
    }
#pragma unroll
    for (int off = 32; off > 0; off >>= 1) {
        s  += __shfl_down(s, off);
        ss += __shfl_down(ss, off);
    }
    s  = __shfl(s, 0);
    ss = __shfl(ss, 0);
    const float mu = s * (1.f / 1024.f);
    const float var = ss * (1.f / 1024.f) - mu * mu;
    const float rs = rsqrtf(var + 1e-5f);
    const float4* gp = (const float4*)g;
    const float4* bp = (const float4*)bt;
#pragma unroll
    for (int k = 0; k < 4; k++) {
        float4 gv = gp[lane + k * 64], bv = bp[lane + k * 64];
        bf16x4 o;
        o[0] = (bf16_t)((xv[k].x - mu) * rs * gv.x + bv.x);
        o[1] = (bf16_t)((xv[k].y - mu) * rs * gv.y + bv.y);
        o[2] = (bf16_t)((xv[k].z - mu) * rs * gv.z + bv.z);
        o[3] = (bf16_t)((xv[k].w - mu) * rs * gv.w + bv.w);
        *(bf16x4*)(out + (size_t)row * 1024 + (lane + k * 64) * 4) = o;
    }
}

__global__ __launch_bounds__(256) void prep_kernel(const float* __restrict__ x,
                                                   const float* __restrict__ ctx,
                                                   const float* __restrict__ g1,
                                                   const float* __restrict__ b1,
                                                   const float* __restrict__ g2,
                                                   const float* __restrict__ b2,
                                                   const float* __restrict__ Wq,
                                                   const float* __restrict__ Wkv,
                                                   const float* __restrict__ Wout,
                                                   bf16_t* __restrict__ xn,
                                                   bf16_t* __restrict__ cn,
                                                   bf16_t* __restrict__ Wqt,
                                                   bf16_t* __restrict__ Wkvt,
                                                   bf16_t* __restrict__ Woutt) {
    int id = blockIdx.x;
    if (id < 128) {
        wtrans_tile(Wq, Wqt, 1024, 512, (id & 7) * 64, (id >> 3) * 64, QSCALE);
    } else if (id < 384) {
        int t = id - 128;
        wtrans_tile(Wkv, Wkvt, 1024, 1024, (t & 15) * 64, (t >> 4) * 64, 1.0f);
    } else if (id < 512) {
        int t = id - 384;
        wtrans_tile(Wout, Woutt, 512, 1024, (t & 15) * 64, (t >> 4) * 64, 1.0f);
    } else {
        int row = (id - 512) * 4 + (threadIdx.x >> 6);   // one row per wave
        if (row < BATCH * SEQ_N) ln_row_wave(x, g1, b1, xn, row);
        else                     ln_row_wave(ctx, g2, b2, cn, row - BATCH * SEQ_N);
    }
}

// ---------------- m97-style GEMM body; NT = col-tile width (128 or 64) ------
// MODE 0: C[row*ldC + col] (+bias). MODE 1 (NT=128): transposed output (V^T):
// operand-swapped MFMA -> D^T in regs -> per-wave LDS transpose -> vector stores.
template <int NT, int MODE, typename OutT>
__device__ __forceinline__ void gemm_body(const bf16_t* __restrict__ A,
                                          const bf16_t* __restrict__ Bt,
                                          OutT* __restrict__ C,
                                          const float* __restrict__ bias,
                                          int ldC, int K, int row0, int col0) {
    __shared__ bf16_t As[128 * 64];
    __shared__ bf16_t Bs[NT * 64];
    const int tid = threadIdx.x;
    const int wave = tid >> 6, lane = tid & 63;
    constexpr int WC = NT / 2;      // wave col extent
    constexpr int NJ = WC / 16;     // 4 or 2
    const int wr = (wave >> 1) * 64, wc = (wave & 1) * WC;
    const int quad = lane >> 4, l16 = lane & 15;

    floatx4 acc[4][NJ] = {};

    for (int k0 = 0; k0 < K; k0 += 64) {
#pragma unroll
        for (int p = 0; p < 4; p++) {
            int cA = p * 256 + wave * 64 + lane;
            int rA = cA >> 3, kc = (cA & 7) * 8;
            __builtin_amdgcn_global_load_lds(
                (gptr_t)(A + (size_t)(row0 + rA) * K + k0 + kc),
                (lptr_t)(As + (size_t)(p * 256 + wave * 64) * 8), 16, 0, 0);
            if (p < NT / 32)
                __builtin_amdgcn_global_load_lds(
                    (gptr_t)(Bt + (size_t)(col0 + rA) * K + k0 + kc),
                    (lptr_t)(Bs + (size_t)(p * 256 + wave * 64) * 8), 16, 0, 0);
        }
        __syncthreads();
#pragma unroll
        for (int kt = 0; kt < 2; kt++) {
            bf16x8 aF[4], bF[NJ];
#pragma unroll
            for (int i = 0; i < 4; i++)
                aF[i] = *(bf16x8*)&As[(wr + i * 16 + l16) * 64 + kt * 32 + quad * 8];
#pragma unroll
            for (int j = 0; j < NJ; j++)
                bF[j] = *(bf16x8*)&Bs[(wc + j * 16 + l16) * 64 + kt * 32 + quad * 8];
#pragma unroll
            for (int i = 0; i < 4; i++)
#pragma unroll
                for (int j = 0; j < NJ; j++) {
                    if (MODE == 0)
                        acc[i][j] = __builtin_amdgcn_mfma_f32_16x16x32_bf16(
                            aF[i], bF[j], acc[i][j], 0, 0, 0);
                    else  // transposed output: D^T
                        acc[i][j] = __builtin_amdgcn_mfma_f32_16x16x32_bf16(
                            bF[j], aF[i], acc[i][j], 0, 0, 0);
                }
        }
        __syncthreads();
    }

    if (MODE == 0) {
#pragma unroll
        for (int i = 0; i < 4; i++)
#pragma unroll
            for (int j = 0; j < NJ; j++) {
                int col = col0 + wc + j * 16 + l16;
                float bv = bias ? bias[col] : 0.f;
#pragma unroll
                for (int r = 0; r < 4; r++) {
                    int row = row0 + wr + i * 16 + quad * 4 + r;
                    C[(size_t)row * ldC + col] = (OutT)(acc[i][j][r] + bv);
                }
            }
    } else {
        // lane holds D^T[d_local = j*16+quad*4+r][m_local = i*16+l16] for wave
        // tile (64 m x 64 d). Transpose via per-wave LDS chunk, then vector-store.
        bf16_t* Tw = (wave < 2 ? As : Bs) + (wave & 1) * 4096;  // 64x64, stride 64
#pragma unroll
        for (int i = 0; i < 4; i++)
#pragma unroll
            for (int j = 0; j < 4; j++)
#pragma unroll
                for (int r = 0; r < 4; r++)
                    Tw[(j * 16 + quad * 4 + r) * 64 + i * 16 + l16] = (bf16_t)acc[i][j][r];
        __syncthreads();
        const int grow = row0 + wr;                  // wave m base (64 aligned)
        const int bat = grow >> 11, gm = (grow & 2047) + l16 * 4;
#pragma unroll
        for (int dd = 0; dd < 16; dd++) {
            int d = dd * 4 + quad;
            bf16x4 v = *(bf16x4*)&Tw[d * 64 + l16 * 4];
            int gd = col0 + wc + d - 512;
            *(bf16x4*)(C + ((size_t)bat * 512 + gd) * 2048 + gm) = v;
        }
    }
}

// Fused q/k/v projections, XCD-chunked 1D grid (768 blocks, 768%8==0):
// each XCD owns 8 consecutive 128-row panels (all 12 col-tiles) -> A-panels
// read once per XCD, weights (<=3MB) stay L2-resident.
__global__ __launch_bounds__(256) void gemm_qkv_kernel(const bf16_t* __restrict__ xn,
                                                       const bf16_t* __restrict__ cn,
                                                       const bf16_t* __restrict__ Wqt,
                                                       const bf16_t* __restrict__ Wkvt,
                                                       bf16_t* __restrict__ qb,
                                                       bf16_t* __restrict__ kvb,
                                                       bf16_t* __restrict__ Vtg) {
    const int f = blockIdx.x;
    const int lb = (f & 7) * 96 + (f >> 3);
    const int bx = lb % 12;
    const int row0 = (lb / 12) * 128;
    if (bx < 4)
        gemm_body<128, 0, bf16_t>(xn, Wqt, qb, nullptr, 512, DIM, row0, bx * 128);
    else if (bx < 8)
        gemm_body<128, 0, bf16_t>(cn, Wkvt, kvb, nullptr, 512, DIM, row0, (bx - 4) * 128);
    else
        gemm_body<128, 1, bf16_t>(cn, Wkvt, Vtg, nullptr, 0, DIM, row0, (bx - 4) * 128);
}

// XCD-chunked 1D grid (1024 blocks): each XCD owns 8 row-panels of ao.
__global__ __launch_bounds__(256) void gemm_out_kernel(const bf16_t* __restrict__ ao,
                                                       const bf16_t* __restrict__ Woutt,
                                                       float* __restrict__ out,
                                                       const float* __restrict__ bias) {
    const int f = blockIdx.x;
    const int lb = (f & 7) * 128 + (f >> 3);
    gemm_body<64, 0, float>(ao, Woutt, out, bias, DIM, INNER,
                            (lb >> 4) * 128, (lb & 15) * 64);
}

// ---------------- Flash attention v8 = v7 inner loop, 256-thread blocks.
// R4/R5/R7 all pin at ~64us with no pipe >50% and occupancy 18-19% (~1.5
// waves/SIMD): latency-bound, not work-bound. v8 raises concurrency ONLY:
// 4 waves x 32 q-rows = 128 q-rows/block, 512 blocks, LDS 48KB -> 3 blocks/CU
// = 12 waves/CU (~37%). Per-score instruction counts unchanged; K/V tile now
// shared by 4 waves (each wave issues 2 K-glds + 2 V-glds per tile, was 4+4).
// Three independent blocks per CU at different phases overlap exp-VALU with
// MFMA/LDS across blocks.
// q: [b,n,512]; kv: [b,m,512] K-only; Vtg: [(b*8+h)*64+d][m]. o: [b,n,512].
__global__ __launch_bounds__(256) void attn_kernel(const bf16_t* __restrict__ q,
                                                   const bf16_t* __restrict__ kv,
                                                   const bf16_t* __restrict__ Vtg,
                                                   bf16_t* __restrict__ o) {
    __shared__ bf16_t Qs[128 * 64];      // Q staging; later per-wave P buffers
    __shared__ bf16_t Ks[2][64 * 64];    // [krow][d] XOR layout, dbuf
    __shared__ bf16_t Vs[2][64 * 64];    // [d][krow] XOR layout, dbuf

    // XCD-chunked block swizzle: 512 blocks, 64 consecutive logical per XCD
    // = 4 (b,h) pairs (~2MB KV per XCD L2).
    const int f = blockIdx.x;
    const int lb = ((f & 7) << 6) | (f >> 3);
    const int b = lb >> 7, h = (lb >> 4) & 7;
    const int n0 = (lb & 15) * 128;

    const int tid = threadIdx.x;
    const int wave = tid >> 6, lane = tid & 63;
    const int quad = lane >> 4, l16 = lane & 15;
    const int swz = (l16 & 7) << 3;          // read-side XOR (row&7 == l16&7)

    const int sr = tid >> 3;                 // Q staging row base (0..31)
    const int sc = (tid & 7) * 8;            // Q staging col
    const int scs = sc ^ ((sr & 7) << 3);    // write-side XOR (row&7 == sr&7)

    // glds staging: wave w owns chunks 2w, 2w+1 (rows 16w .. 16w+15).
    // lane covers row rloc=(lane>>3) of an 8-row chunk, 16B col chunk (lane&7);
    // source col pre-swizzled so linear LDS dest == XOR layout.
    const int rloc = lane >> 3;                        // 0..7
    const int srccol = ((lane & 7) ^ rloc) << 3;       // (a ^ r)*8 elems
    const bf16_t* kgl = kv + ((size_t)(b * SEQ_M) + wave * 16 + rloc) * 512
                           + h * DHEAD + srccol;
    const bf16_t* vgl = Vtg + ((size_t)((b * HEADS + h) * DHEAD)
                               + wave * 16 + rloc) * SEQ_M + srccol;

    // issue K/V tile 0 -> buf 0 (drained by the vmcnt(0) at the first barrier)
#pragma unroll
    for (int p = 0; p < 2; p++) {
        __builtin_amdgcn_global_load_lds(
            (gptr_t)(kgl + (size_t)(p * 8) * 512),
            (lptr_t)(Ks[0] + (wave * 2 + p) * 512), 16, 0, 0);
        __builtin_amdgcn_global_load_lds(
            (gptr_t)(vgl + (size_t)(p * 8) * SEQ_M),
            (lptr_t)(Vs[0] + (wave * 2 + p) * 512), 16, 0, 0);
    }

    // stage Q tile [128][64] (swizzled, reg path)
#pragma unroll
    for (int p = 0; p < 4; p++) {
        int r = sr + p * 32;
        *(bf16x8*)&Qs[r * 64 + scs] =
            *(const bf16x8*)(q + (size_t)(b * SEQ_N + n0 + r) * INNER + h * DHEAD + sc);
    }

    // ones B-frag for the l-column MFMA: B[k][n=l16] = (l16==0) ? 1 : 0
    bf16x8 bOnes;
    {
        bf16_t ov = (l16 == 0) ? (bf16_t)1.0f : (bf16_t)0.0f;
#pragma unroll
        for (int i = 0; i < 8; i++) bOnes[i] = ov;
    }

    __syncthreads();     // Q visible; K0/V0 drained

    // per-wave Q fragments: 2 sets of 16 q-rows (rows wave*32 .. wave*32+31)
    bf16x8 aQ0[2], aQ1[2];
#pragma unroll
    for (int kt = 0; kt < 2; kt++) {
        aQ0[kt] = *(bf16x8*)&Qs[(wave * 32 + l16) * 64 + ((kt * 32 + quad * 8) ^ swz)];
        aQ1[kt] = *(bf16x8*)&Qs[(wave * 32 + 16 + l16) * 64 + ((kt * 32 + quad * 8) ^ swz)];
    }

    // issue K/V tile 1 -> buf 1 (in flight during iter 0)
    kgl += (size_t)64 * 512;
    vgl += 64;
#pragma unroll
    for (int p = 0; p < 2; p++) {
        __builtin_amdgcn_global_load_lds(
            (gptr_t)(kgl + (size_t)(p * 8) * 512),
            (lptr_t)(Ks[1] + (wave * 2 + p) * 512), 16, 0, 0);
        __builtin_amdgcn_global_load_lds(
            (gptr_t)(vgl + (size_t)(p * 8) * SEQ_M),
            (lptr_t)(Vs[1] + (wave * 2 + p) * 512), 16, 0, 0);
    }

    // per-wave P buffers alias this wave's (already-consumed) Qs rows
    bf16_t* Pw0 = Qs + wave * 2048;          // set 0: rows wave*32..+15
    bf16_t* Pw1 = Pw0 + 1024;                // set 1: rows wave*32+16..+31

    floatx4 oacc0[5] = {}, oacc1[5] = {};    // [0..3]=O d-tiles, [4]=l (col 0)

    int cur = 0;
    for (int it = 0; it < SEQ_M / 64; ++it) {
        // S^T = K @ Q^T (exp2 domain): aK read once, feeds BOTH q-sets
        floatx4 s0[4] = {}, s1[4] = {};
        __builtin_amdgcn_s_setprio(1);
#pragma unroll
        for (int kt = 0; kt < 2; kt++)
#pragma unroll
            for (int jt = 0; jt < 4; jt++) {
                bf16x8 aK = *(bf16x8*)&Ks[cur][(jt * 16 + l16) * 64 +
                                              ((kt * 32 + quad * 8) ^ swz)];
                s0[jt] = __builtin_amdgcn_mfma_f32_16x16x32_bf16(aK, aQ0[kt], s0[jt], 0, 0, 0);
                s1[jt] = __builtin_amdgcn_mfma_f32_16x16x32_bf16(aK, aQ1[kt], s1[jt], 0, 0, 0);
            }
        __builtin_amdgcn_s_setprio(0);

        // P = exp2(S^T): packed b64 stores at P[q=l16][m=jt*16+quad*4]
#pragma unroll
        for (int jt = 0; jt < 4; jt++) {
            bf16x4 pk0, pk1;
#pragma unroll
            for (int r = 0; r < 4; r++) {
                pk0[r] = (bf16_t)fast_exp2(s0[jt][r]);
                pk1[r] = (bf16_t)fast_exp2(s1[jt][r]);
            }
            int pc = (jt * 16 + quad * 4) ^ swz;
            *(bf16x4*)&Pw0[l16 * 64 + pc] = pk0;
            *(bf16x4*)&Pw1[l16 * 64 + pc] = pk1;
        }

        // O += P @ V; bV read once, feeds BOTH q-sets; l via register ones-frag
        __builtin_amdgcn_s_setprio(1);
#pragma unroll
        for (int kt = 0; kt < 2; kt++) {
            int ac = (kt * 32 + quad * 8) ^ swz;
            bf16x8 aP0 = *(bf16x8*)&Pw0[l16 * 64 + ac];
            bf16x8 aP1 = *(bf16x8*)&Pw1[l16 * 64 + ac];
#pragma unroll
            for (int dt = 0; dt < 4; dt++) {
                bf16x8 bV = *(bf16x8*)&Vs[cur][(dt * 16 + l16) * 64 + ac];
                oacc0[dt] = __builtin_amdgcn_mfma_f32_16x16x32_bf16(aP0, bV, oacc0[dt], 0, 0, 0);
                oacc1[dt] = __builtin_amdgcn_mfma_f32_16x16x32_bf16(aP1, bV, oacc1[dt], 0, 0, 0);
            }
            oacc0[4] = __builtin_amdgcn_mfma_f32_16x16x32_bf16(aP0, bOnes, oacc0[4], 0, 0, 0);
            oacc1[4] = __builtin_amdgcn_mfma_f32_16x16x32_bf16(aP1, bOnes, oacc1[4], 0, 0, 0);
        }
        __builtin_amdgcn_s_setprio(0);

        __syncthreads();     // tile-it reads retired; K/V(it+1) glds drained

        // issue K/V(it+2) into the buffer just freed (in flight a full iter;
        // OOB tail reads land in owned ws regions, unused)
        kgl += (size_t)64 * 512;
        vgl += 64;
#pragma unroll
        for (int p = 0; p < 2; p++) {
            __builtin_amdgcn_global_load_lds(
                (gptr_t)(kgl + (size_t)(p * 8) * 512),
                (lptr_t)(Ks[cur] + (wave * 2 + p) * 512), 16, 0, 0);
            __builtin_amdgcn_global_load_lds(
                (gptr_t)(vgl + (size_t)(p * 8) * SEQ_M),
                (lptr_t)(Vs[cur] + (wave * 2 + p) * 512), 16, 0, 0);
        }
        cur ^= 1;
    }

    // epilogue: l in oacc*[4] col 0; broadcast within quad-row group
#pragma unroll
    for (int set = 0; set < 2; set++) {
        const floatx4* oa = set == 0 ? oacc0 : oacc1;   // compile-time select
        float inv[4];
#pragma unroll
        for (int r = 0; r < 4; r++) {
            float l = __shfl(oa[4][r], (int)(lane & 48));
            inv[r] = 1.0f / l;
        }
#pragma unroll
        for (int dt = 0; dt < 4; dt++)
#pragma unroll
            for (int r = 0; r < 4; r++) {
                int row = n0 + wave * 32 + set * 16 + quad * 4 + r;
                int col = h * DHEAD + dt * 16 + l16;
                o[(size_t)(b * SEQ_N + row) * INNER + col] =
                    (bf16_t)(oa[dt][r] * inv[r]);
            }
    }
}

extern "C" void kernel_launch(void* const* d_in, const int* in_sizes, int n_in,
                              void* d_out, int out_size, void* d_ws, size_t ws_size,
                              hipStream_t stream) {
    const float* x    = (const float*)d_in[0];
    const float* ctx  = (const float*)d_in[1];
    const float* g1   = (const float*)d_in[2];
    const float* b1   = (const float*)d_in[3];
    const float* g2   = (const float*)d_in[4];
    const float* b2   = (const float*)d_in[5];
    const float* Wq   = (const float*)d_in[6];
    const float* Wkv  = (const float*)d_in[7];
    const float* Wout = (const float*)d_in[8];
    const float* bout = (const float*)d_in[9];
    float* out = (float*)d_out;

    const int rows = BATCH * SEQ_N;  // 8192
    bf16_t* xn    = (bf16_t*)d_ws;                       // 8M elem; reused as attn out
    bf16_t* cn    = xn + (size_t)rows * DIM;             // 8M
    bf16_t* qb    = cn + (size_t)rows * DIM;             // 4M
    bf16_t* kvb   = qb + (size_t)rows * INNER;           // 4M (K only, stride 512)
    bf16_t* Vtg   = kvb + (size_t)rows * INNER;          // 4M (V transposed)
    bf16_t* Wqt   = Vtg + (size_t)rows * INNER;          // 0.5M
    bf16_t* Wkvt  = Wqt + (size_t)INNER * DIM;           // 1M
    bf16_t* Woutt = Wkvt + (size_t)(2 * INNER) * DIM;    // 0.5M
    bf16_t* o_attn = xn;  // alias: xn dead after qkv GEMM

    prep_kernel<<<512 + (2 * rows) / 4, 256, 0, stream>>>(
        x, ctx, g1, b1, g2, b2, Wq, Wkv, Wout, xn, cn, Wqt, Wkvt, Woutt);
    gemm_qkv_kernel<<<768, 256, 0, stream>>>(
        xn, cn, Wqt, Wkvt, qb, kvb, Vtg);
    attn_kernel<<<512, 256, 0, stream>>>(qb, kvb, Vtg, o_attn);
    gemm_out_kernel<<<1024, 256, 0, stream>>>(o_attn, Woutt, out, bout);
}

// Round 9
// 231.731 us; speedup vs baseline: 1.0573x; 1.0332x over previous
//
#include <hip/hip_runtime.h>
#include <hip/hip_bf16.h>

typedef __bf16 bf16_t;
typedef bf16_t bf16x4 __attribute__((ext_vector_type(4)));
typedef bf16_t bf16x8 __attribute__((ext_vector_type(8)));
typedef float floatx4 __attribute__((ext_vector_type(4)));

typedef __attribute__((address_space(1))) const unsigned char* gptr_t;
typedef __attribute__((address_space(3))) unsigned char* lptr_t;

#define BATCH 4
#define SEQ_N 2048
#define SEQ_M 2048
#define DIM 1024
#define INNER 512
#define HEADS 8
#define DHEAD 64
// 0.125 * log2(e): folded into Wq so attention scores arrive in exp2 domain
#define QSCALE 0.18033688011112042f

// Raw hardware exp2 via compiler-visible builtin (R4-verified: -20 µs, safe).
#if __has_builtin(__builtin_amdgcn_exp2f)
#define fast_exp2(x) __builtin_amdgcn_exp2f(x)
#else
#define fast_exp2(x) exp2f(x)
#endif

// ---------------- Prep: weight convert+transpose AND LayerNorm, one dispatch
__device__ __forceinline__ void wtrans_tile(const float* W, bf16_t* Wt,
                                            int K, int N, int n0, int k0, float scale) {
    __shared__ bf16_t T[64][72];
    const int tid = threadIdx.x;
#pragma unroll
    for (int p = 0; p < 2; p++) {
        int r = (tid >> 3) + p * 32;       // k
        int c = (tid & 7) * 8;             // n
        const float* src = W + (size_t)(k0 + r) * N + n0 + c;
        float4 v0 = *(const float4*)src;
        float4 v1 = *(const float4*)(src + 4);
        T[r][c + 0] = (bf16_t)(v0.x * scale); T[r][c + 1] = (bf16_t)(v0.y * scale);
        T[r][c + 2] = (bf16_t)(v0.z * scale); T[r][c + 3] = (bf16_t)(v0.w * scale);
        T[r][c + 4] = (bf16_t)(v1.x * scale); T[r][c + 5] = (bf16_t)(v1.y * scale);
        T[r][c + 6] = (bf16_t)(v1.z * scale); T[r][c + 7] = (bf16_t)(v1.w * scale);
    }
    __syncthreads();
#pragma unroll
    for (int p = 0; p < 2; p++) {
        int rn = (tid >> 3) + p * 32;      // n
        int ck = (tid & 7) * 8;            // k
        bf16x8 v;
#pragma unroll
        for (int i = 0; i < 8; i++) v[i] = T[ck + i][rn];
        *(bf16x8*)(Wt + (size_t)(n0 + rn) * K + k0 + ck) = v;
    }
}

// One LN row per wave: shuffle-only reduction, no barriers, no LDS.
__device__ __forceinline__ void ln_row_wave(const float* in, const float* g,
                                            const float* bt, bf16_t* out, int row) {
    const int lane = threadIdx.x & 63;
    const float4* src = (const float4*)(in + (size_t)row * 1024);
    float4 xv[4];
    float s = 0.f, ss = 0.f;
#pragma unroll
    for (int k = 0; k < 4; k++) {
        xv[k] = src[lane + k * 64];
        s  += xv[k].x + xv[k].y + xv[k].z + xv[k].w;
        ss += xv[k].x * xv[k].x + xv[k].y * xv[k].y + xv[k].z * xv[k].z + xv[k].w * xv[k].w;
    }
#pragma unroll
    for (int off = 32; off > 0; off >>= 1) {
        s  += __shfl_down(s, off);
        ss += __shfl_down(ss, off);
    }
    s  = __shfl(s, 0);
    ss = __shfl(ss, 0);
    const float mu = s * (1.f / 1024.f);
    const float var = ss * (1.f / 1024.f) - mu * mu;
    const float rs = rsqrtf(var + 1e-5f);
    const float4* gp = (const float4*)g;
    const float4* bp = (const float4*)bt;
#pragma unroll
    for (int k = 0; k < 4; k++) {
        float4 gv = gp[lane + k * 64], bv = bp[lane + k * 64];
        bf16x4 o;
        o[0] = (bf16_t)((xv[k].x - mu) * rs * gv.x + bv.x);
        o[1] = (bf16_t)((xv[k].y - mu) * rs * gv.y + bv.y);
        o[2] = (bf16_t)((xv[k].z - mu) * rs * gv.z + bv.z);
        o[3] = (bf16_t)((xv[k].w - mu) * rs * gv.w + bv.w);
        *(bf16x4*)(out + (size_t)row * 1024 + (lane + k * 64) * 4) = o;
    }
}

__global__ __launch_bounds__(256) void prep_kernel(const float* __restrict__ x,
                                                   const float* __restrict__ ctx,
                                                   const float* __restrict__ g1,
                                                   const float* __restrict__ b1,
                                                   const float* __restrict__ g2,
                                                   const float* __restrict__ b2,
                                                   const float* __restrict__ Wq,
                                                   const float* __restrict__ Wkv,
                                                   const float* __restrict__ Wout,
                                                   bf16_t* __restrict__ xn,
                                                   bf16_t* __restrict__ cn,
                                                   bf16_t* __restrict__ Wqt,
                                                   bf16_t* __restrict__ Wkvt,
                                                   bf16_t* __restrict__ Woutt) {
    int id = blockIdx.x;
    if (id < 128) {
        wtrans_tile(Wq, Wqt, 1024, 512, (id & 7) * 64, (id >> 3) * 64, QSCALE);
    } else if (id < 384) {
        int t = id - 128;
        wtrans_tile(Wkv, Wkvt, 1024, 1024, (t & 15) * 64, (t >> 4) * 64, 1.0f);
    } else if (id < 512) {
        int t = id - 384;
        wtrans_tile(Wout, Woutt, 512, 1024, (t & 15) * 64, (t >> 4) * 64, 1.0f);
    } else {
        int row = (id - 512) * 4 + (threadIdx.x >> 6);   // one row per wave
        if (row < BATCH * SEQ_N) ln_row_wave(x, g1, b1, xn, row);
        else                     ln_row_wave(ctx, g2, b2, cn, row - BATCH * SEQ_N);
    }
}

// ---------------- m97-style GEMM body; NT = col-tile width (128 or 64) ------
// MODE 0: C[row*ldC + col] (+bias). MODE 1 (NT=128): transposed output (V^T):
// operand-swapped MFMA -> D^T in regs -> per-wave LDS transpose -> vector stores.
template <int NT, int MODE, typename OutT>
__device__ __forceinline__ void gemm_body(const bf16_t* __restrict__ A,
                                          const bf16_t* __restrict__ Bt,
                                          OutT* __restrict__ C,
                                          const float* __restrict__ bias,
                                          int ldC, int K, int row0, int col0) {
    __shared__ bf16_t As[128 * 64];
    __shared__ bf16_t Bs[NT * 64];
    const int tid = threadIdx.x;
    const int wave = tid >> 6, lane = tid & 63;
    constexpr int WC = NT / 2;      // wave col extent
    constexpr int NJ = WC / 16;     // 4 or 2
    const int wr = (wave >> 1) * 64, wc = (wave & 1) * WC;
    const int quad = lane >> 4, l16 = lane & 15;

    floatx4 acc[4][NJ] = {};

    for (int k0 = 0; k0 < K; k0 += 64) {
#pragma unroll
        for (int p = 0; p < 4; p++) {
            int cA = p * 256 + wave * 64 + lane;
            int rA = cA >> 3, kc = (cA & 7) * 8;
            __builtin_amdgcn_global_load_lds(
                (gptr_t)(A + (size_t)(row0 + rA) * K + k0 + kc),
                (lptr_t)(As + (size_t)(p * 256 + wave * 64) * 8), 16, 0, 0);
            if (p < NT / 32)
                __builtin_amdgcn_global_load_lds(
                    (gptr_t)(Bt + (size_t)(col0 + rA) * K + k0 + kc),
                    (lptr_t)(Bs + (size_t)(p * 256 + wave * 64) * 8), 16, 0, 0);
        }
        __syncthreads();
#pragma unroll
        for (int kt = 0; kt < 2; kt++) {
            bf16x8 aF[4], bF[NJ];
#pragma unroll
            for (int i = 0; i < 4; i++)
                aF[i] = *(bf16x8*)&As[(wr + i * 16 + l16) * 64 + kt * 32 + quad * 8];
#pragma unroll
            for (int j = 0; j < NJ; j++)
                bF[j] = *(bf16x8*)&Bs[(wc + j * 16 + l16) * 64 + kt * 32 + quad * 8];
#pragma unroll
            for (int i = 0; i < 4; i++)
#pragma unroll
                for (int j = 0; j < NJ; j++) {
                    if (MODE == 0)
                        acc[i][j] = __builtin_amdgcn_mfma_f32_16x16x32_bf16(
                            aF[i], bF[j], acc[i][j], 0, 0, 0);
                    else  // transposed output: D^T
                        acc[i][j] = __builtin_amdgcn_mfma_f32_16x16x32_bf16(
                            bF[j], aF[i], acc[i][j], 0, 0, 0);
                }
        }
        __syncthreads();
    }

    if (MODE == 0) {
#pragma unroll
        for (int i = 0; i < 4; i++)
#pragma unroll
            for (int j = 0; j < NJ; j++) {
                int col = col0 + wc + j * 16 + l16;
                float bv = bias ? bias[col] : 0.f;
#pragma unroll
                for (int r = 0; r < 4; r++) {
                    int row = row0 + wr + i * 16 + quad * 4 + r;
                    C[(size_t)row * ldC + col] = (OutT)(acc[i][j][r] + bv);
                }
            }
    } else {
        // lane holds D^T[d_local = j*16+quad*4+r][m_local = i*16+l16] for wave
        // tile (64 m x 64 d). Transpose via per-wave LDS chunk, then vector-store.
        bf16_t* Tw = (wave < 2 ? As : Bs) + (wave & 1) * 4096;  // 64x64, stride 64
#pragma unroll
        for (int i = 0; i < 4; i++)
#pragma unroll
            for (int j = 0; j < 4; j++)
#pragma unroll
                for (int r = 0; r < 4; r++)
                    Tw[(j * 16 + quad * 4 + r) * 64 + i * 16 + l16] = (bf16_t)acc[i][j][r];
        __syncthreads();
        const int grow = row0 + wr;                  // wave m base (64 aligned)
        const int bat = grow >> 11, gm = (grow & 2047) + l16 * 4;
#pragma unroll
        for (int dd = 0; dd < 16; dd++) {
            int d = dd * 4 + quad;
            bf16x4 v = *(bf16x4*)&Tw[d * 64 + l16 * 4];
            int gd = col0 + wc + d - 512;
            *(bf16x4*)(C + ((size_t)bat * 512 + gd) * 2048 + gm) = v;
        }
    }
}

// Fused q/k/v projections, XCD-chunked 1D grid (768 blocks, 768%8==0):
// each XCD owns 8 consecutive 128-row panels (all 12 col-tiles) -> A-panels
// read once per XCD, weights (<=3MB) stay L2-resident.
__global__ __launch_bounds__(256) void gemm_qkv_kernel(const bf16_t* __restrict__ xn,
                                                       const bf16_t* __restrict__ cn,
                                                       const bf16_t* __restrict__ Wqt,
                                                       const bf16_t* __restrict__ Wkvt,
                                                       bf16_t* __restrict__ qb,
                                                       bf16_t* __restrict__ kvb,
                                                       bf16_t* __restrict__ Vtg) {
    const int f = blockIdx.x;
    const int lb = (f & 7) * 96 + (f >> 3);
    const int bx = lb % 12;
    const int row0 = (lb / 12) * 128;
    if (bx < 4)
        gemm_body<128, 0, bf16_t>(xn, Wqt, qb, nullptr, 512, DIM, row0, bx * 128);
    else if (bx < 8)
        gemm_body<128, 0, bf16_t>(cn, Wkvt, kvb, nullptr, 512, DIM, row0, (bx - 4) * 128);
    else
        gemm_body<128, 1, bf16_t>(cn, Wkvt, Vtg, nullptr, 0, DIM, row0, (bx - 4) * 128);
}

// XCD-chunked 1D grid (1024 blocks): each XCD owns 8 row-panels of ao.
__global__ __launch_bounds__(256) void gemm_out_kernel(const bf16_t* __restrict__ ao,
                                                       const bf16_t* __restrict__ Woutt,
                                                       float* __restrict__ out,
                                                       const float* __restrict__ bias) {
    const int f = blockIdx.x;
    const int lb = (f & 7) * 128 + (f >> 3);
    gemm_body<64, 0, float>(ao, Woutt, out, bias, DIM, INNER,
                            (lb >> 4) * 128, (lb & 15) * 64);
}

// ---------------- Flash attention v9 = v8 + cross-iteration software pipeline.
// R8 diagnosis: no pipe >50%; occupancy grid-capped at 2 blocks/CU (512 blocks);
// per-wave serial chain QK->exp->PV (~750cyc) is the wall. v9 carries S(it) in
// registers and reorders the body to [exp/pack P(it); QK(it+1); PV(it)]:
// QK(it+1) is independent of exp(it) -> compiler interleaves MFMA issue under
// the exp VALU phase; only PV waits on P. Requires tile it+1 readable during
// iter it -> TRIPLE-buffered K/V (3x16KB + Qs 16KB = 64KB; still 2 blocks/CU,
// which the 512-block grid caps anyway -> zero occupancy cost).
// Buffer timeline: glds(t) issued after barrier(t-3), drained at barrier(t-2),
// first read QK(t) in iter t-1, last read PV(t) in iter t, refilled after
// barrier(t) with tile t+3.
// q: [b,n,512]; kv: [b,m,512] K-only; Vtg: [(b*8+h)*64+d][m]. o: [b,n,512].
__global__ __launch_bounds__(256, 2) void attn_kernel(const bf16_t* __restrict__ q,
                                                      const bf16_t* __restrict__ kv,
                                                      const bf16_t* __restrict__ Vtg,
                                                      bf16_t* __restrict__ o) {
    __shared__ bf16_t Qs[128 * 64];      // Q staging; later per-wave P buffers
    __shared__ bf16_t Ks[3][64 * 64];    // [krow][d] XOR layout, triple-buffered
    __shared__ bf16_t Vs[3][64 * 64];    // [d][krow] XOR layout, triple-buffered

    // XCD-chunked block swizzle: 512 blocks, 64 consecutive logical per XCD
    // = 4 (b,h) pairs (~2MB KV per XCD L2).
    const int f = blockIdx.x;
    const int lb = ((f & 7) << 6) | (f >> 3);
    const int b = lb >> 7, h = (lb >> 4) & 7;
    const int n0 = (lb & 15) * 128;

    const int tid = threadIdx.x;
    const int wave = tid >> 6, lane = tid & 63;
    const int quad = lane >> 4, l16 = lane & 15;
    const int swz = (l16 & 7) << 3;          // read-side XOR (row&7 == l16&7)

    const int sr = tid >> 3;                 // Q staging row base (0..31)
    const int sc = (tid & 7) * 8;            // Q staging col
    const int scs = sc ^ ((sr & 7) << 3);    // write-side XOR (row&7 == sr&7)

    // glds staging: wave w owns chunks 2w, 2w+1 (rows 16w..16w+15); lane covers
    // row rloc=(lane>>3) of an 8-row chunk, 16B col chunk (lane&7); source col
    // pre-swizzled so linear LDS dest == XOR layout.
    const int rloc = lane >> 3;                        // 0..7
    const int srccol = ((lane & 7) ^ rloc) << 3;       // (a ^ r)*8 elems
    const bf16_t* kgl = kv + ((size_t)(b * SEQ_M) + wave * 16 + rloc) * 512
                           + h * DHEAD + srccol;
    const bf16_t* vgl = Vtg + ((size_t)((b * HEADS + h) * DHEAD)
                               + wave * 16 + rloc) * SEQ_M + srccol;

    // stage one 64-row K/V tile into (KD,VD), advance source to next tile
    auto STAGE = [&](bf16_t* KD, bf16_t* VD) {
#pragma unroll
        for (int p = 0; p < 2; p++) {
            __builtin_amdgcn_global_load_lds(
                (gptr_t)(kgl + (size_t)(p * 8) * 512),
                (lptr_t)(KD + (wave * 2 + p) * 512), 16, 0, 0);
            __builtin_amdgcn_global_load_lds(
                (gptr_t)(vgl + (size_t)(p * 8) * SEQ_M),
                (lptr_t)(VD + (wave * 2 + p) * 512), 16, 0, 0);
        }
        kgl += (size_t)64 * 512;
        vgl += 64;
    };

    STAGE(Ks[0], Vs[0]);     // tile 0
    STAGE(Ks[1], Vs[1]);     // tile 1 (both drained at the first barrier)

    // stage Q tile [128][64] (swizzled, reg path)
#pragma unroll
    for (int p = 0; p < 4; p++) {
        int r = sr + p * 32;
        *(bf16x8*)&Qs[r * 64 + scs] =
            *(const bf16x8*)(q + (size_t)(b * SEQ_N + n0 + r) * INNER + h * DHEAD + sc);
    }

    // ones B-frag for the l-column MFMA: B[k][n=l16] = (l16==0) ? 1 : 0
    bf16x8 bOnes;
    {
        bf16_t ov = (l16 == 0) ? (bf16_t)1.0f : (bf16_t)0.0f;
#pragma unroll
        for (int i = 0; i < 8; i++) bOnes[i] = ov;
    }

    __syncthreads();     // Q visible; tiles 0,1 drained

    // per-wave Q fragments: 2 sets of 16 q-rows (rows wave*32 .. wave*32+31)
    bf16x8 aQ0[2], aQ1[2];
#pragma unroll
    for (int kt = 0; kt < 2; kt++) {
        aQ0[kt] = *(bf16x8*)&Qs[(wave * 32 + l16) * 64 + ((kt * 32 + quad * 8) ^ swz)];
        aQ1[kt] = *(bf16x8*)&Qs[(wave * 32 + 16 + l16) * 64 + ((kt * 32 + quad * 8) ^ swz)];
    }

    STAGE(Ks[2], Vs[2]);     // tile 2 in flight during iter 0

    // S^T = K @ Q^T (exp2 domain): aK read once, feeds BOTH q-sets
    auto QK = [&](const bf16_t* KB, floatx4* d0, floatx4* d1) {
#pragma unroll
        for (int kt = 0; kt < 2; kt++)
#pragma unroll
            for (int jt = 0; jt < 4; jt++) {
                bf16x8 aK = *(bf16x8*)&KB[(jt * 16 + l16) * 64 +
                                          ((kt * 32 + quad * 8) ^ swz)];
                d0[jt] = __builtin_amdgcn_mfma_f32_16x16x32_bf16(aK, aQ0[kt], d0[jt], 0, 0, 0);
                d1[jt] = __builtin_amdgcn_mfma_f32_16x16x32_bf16(aK, aQ1[kt], d1[jt], 0, 0, 0);
            }
    };

    // per-wave P buffers alias this wave's (already-consumed) Qs rows
    bf16_t* Pw0 = Qs + wave * 2048;          // set 0: rows wave*32..+15
    bf16_t* Pw1 = Pw0 + 1024;                // set 1: rows wave*32+16..+31

    floatx4 oacc0[5] = {}, oacc1[5] = {};    // [0..3]=O d-tiles, [4]=l (col 0)

    // rotating buffer roles: c=tile it (PV), n=tile it+1 (QK), x=in-flight
    bf16_t *cK = Ks[0], *cV = Vs[0];
    bf16_t *nK = Ks[1], *nV = Vs[1];
    bf16_t *xK = Ks[2], *xV = Vs[2];

    // prologue: S(0) from tile 0
    floatx4 s0[4] = {}, s1[4] = {};
    QK(cK, s0, s1);

    for (int it = 0; it < SEQ_M / 64; ++it) {
        // P(it) = exp2(S(it)): packed b64 stores at P[q=l16][m=jt*16+quad*4]
#pragma unroll
        for (int jt = 0; jt < 4; jt++) {
            bf16x4 pk0, pk1;
#pragma unroll
            for (int r = 0; r < 4; r++) {
                pk0[r] = (bf16_t)fast_exp2(s0[jt][r]);
                pk1[r] = (bf16_t)fast_exp2(s1[jt][r]);
            }
            int pc = (jt * 16 + quad * 4) ^ swz;
            *(bf16x4*)&Pw0[l16 * 64 + pc] = pk0;
            *(bf16x4*)&Pw1[l16 * 64 + pc] = pk1;
        }

        __builtin_amdgcn_s_setprio(1);
        // QK(it+1) from nK — independent of exp above: compiler interleaves
        floatx4 t0[4] = {}, t1[4] = {};
        QK(nK, t0, t1);

        // PV(it): O += P(it) @ V(it); l via register ones-frag
#pragma unroll
        for (int kt = 0; kt < 2; kt++) {
            int ac = (kt * 32 + quad * 8) ^ swz;
            bf16x8 aP0 = *(bf16x8*)&Pw0[l16 * 64 + ac];
            bf16x8 aP1 = *(bf16x8*)&Pw1[l16 * 64 + ac];
#pragma unroll
            for (int dt = 0; dt < 4; dt++) {
                bf16x8 bV = *(bf16x8*)&cV[(dt * 16 + l16) * 64 + ac];
                oacc0[dt] = __builtin_amdgcn_mfma_f32_16x16x32_bf16(aP0, bV, oacc0[dt], 0, 0, 0);
                oacc1[dt] = __builtin_amdgcn_mfma_f32_16x16x32_bf16(aP1, bV, oacc1[dt], 0, 0, 0);
            }
            oacc0[4] = __builtin_amdgcn_mfma_f32_16x16x32_bf16(aP0, bOnes, oacc0[4], 0, 0, 0);
            oacc1[4] = __builtin_amdgcn_mfma_f32_16x16x32_bf16(aP1, bOnes, oacc1[4], 0, 0, 0);
        }
        __builtin_amdgcn_s_setprio(0);

        __syncthreads();     // all waves: PV(it) done (cV free), glds(it+2) drained

        // refill the just-freed buffer with tile it+3 (in flight a full iter;
        // OOB tail reads land in adjacent ws regions, unused)
        STAGE(cK, cV);

        // rotate roles and carry S(it+1)
        bf16_t* t;
        t = cK; cK = nK; nK = xK; xK = t;
        t = cV; cV = nV; nV = xV; xV = t;
#pragma unroll
        for (int jt = 0; jt < 4; jt++) { s0[jt] = t0[jt]; s1[jt] = t1[jt]; }
    }

    // epilogue: l in oacc*[4] col 0; broadcast within quad-row group
#pragma unroll
    for (int set = 0; set < 2; set++) {
        const floatx4* oa = set == 0 ? oacc0 : oacc1;   // compile-time select
        float inv[4];
#pragma unroll
        for (int r = 0; r < 4; r++) {
            float l = __shfl(oa[4][r], (int)(lane & 48));
            inv[r] = 1.0f / l;
        }
#pragma unroll
        for (int dt = 0; dt < 4; dt++)
#pragma unroll
            for (int r = 0; r < 4; r++) {
                int row = n0 + wave * 32 + set * 16 + quad * 4 + r;
                int col = h * DHEAD + dt * 16 + l16;
                o[(size_t)(b * SEQ_N + row) * INNER + col] =
                    (bf16_t)(oa[dt][r] * inv[r]);
            }
    }
}

extern "C" void kernel_launch(void* const* d_in, const int* in_sizes, int n_in,
                              void* d_out, int out_size, void* d_ws, size_t ws_size,
                              hipStream_t stream) {
    const float* x    = (const float*)d_in[0];
    const float* ctx  = (const float*)d_in[1];
    const float* g1   = (const float*)d_in[2];
    const float* b1   = (const float*)d_in[3];
    const float* g2   = (const float*)d_in[4];
    const float* b2   = (const float*)d_in[5];
    const float* Wq   = (const float*)d_in[6];
    const float* Wkv  = (const float*)d_in[7];
    const float* Wout = (const float*)d_in[8];
    const float* bout = (const float*)d_in[9];
    float* out = (float*)d_out;

    const int rows = BATCH * SEQ_N;  // 8192
    bf16_t* xn    = (bf16_t*)d_ws;                       // 8M elem; reused as attn out
    bf16_t* cn    = xn + (size_t)rows * DIM;             // 8M
    bf16_t* qb    = cn + (size_t)rows * DIM;             // 4M
    bf16_t* kvb   = qb + (size_t)rows * INNER;           // 4M (K only, stride 512)
    bf16_t* Vtg   = kvb + (size_t)rows * INNER;          // 4M (V transposed)
    bf16_t* Wqt   = Vtg + (size_t)rows * INNER;          // 0.5M
    bf16_t* Wkvt  = Wqt + (size_t)INNER * DIM;           // 1M
    bf16_t* Woutt = Wkvt + (size_t)(2 * INNER) * DIM;    // 0.5M
    bf16_t* o_attn = xn;  // alias: xn dead after qkv GEMM

    prep_kernel<<<512 + (2 * rows) / 4, 256, 0, stream>>>(
        x, ctx, g1, b1, g2, b2, Wq, Wkv, Wout, xn, cn, Wqt, Wkvt, Woutt);
    gemm_qkv_kernel<<<768, 256, 0, stream>>>(
        xn, cn, Wqt, Wkvt, qb, kvb, Vtg);
    attn_kernel<<<512, 256, 0, stream>>>(qb, kvb, Vtg, o_attn);
    gemm_out_kernel<<<1024, 256, 0, stream>>>(o_attn, Woutt, out, bout);
}

// Round 10
// 220.753 us; speedup vs baseline: 1.1099x; 1.0497x over previous
//
#include <hip/hip_runtime.h>
#include <hip/hip_bf16.h>

typedef __bf16 bf16_t;
typedef bf16_t bf16x4 __attribute__((ext_vector_type(4)));
typedef bf16_t bf16x8 __attribute__((ext_vector_type(8)));
typedef float floatx4 __attribute__((ext_vector_type(4)));

typedef __attribute__((address_space(1))) const unsigned char* gptr_t;
typedef __attribute__((address_space(3))) unsigned char* lptr_t;

#define BATCH 4
#define SEQ_N 2048
#define SEQ_M 2048
#define DIM 1024
#define INNER 512
#define HEADS 8
#define DHEAD 64
// 0.125 * log2(e): folded into Wq so attention scores arrive in exp2 domain
#define QSCALE 0.18033688011112042f

// Raw hardware exp2 via compiler-visible builtin (R4-verified: -20 µs, safe).
#if __has_builtin(__builtin_amdgcn_exp2f)
#define fast_exp2(x) __builtin_amdgcn_exp2f(x)
#else
#define fast_exp2(x) exp2f(x)
#endif

// ---------------- Prep: weight convert+transpose AND LayerNorm, one dispatch
__device__ __forceinline__ void wtrans_tile(const float* W, bf16_t* Wt,
                                            int K, int N, int n0, int k0, float scale) {
    __shared__ bf16_t T[64][72];
    const int tid = threadIdx.x;
#pragma unroll
    for (int p = 0; p < 2; p++) {
        int r = (tid >> 3) + p * 32;       // k
        int c = (tid & 7) * 8;             // n
        const float* src = W + (size_t)(k0 + r) * N + n0 + c;
        float4 v0 = *(const float4*)src;
        float4 v1 = *(const float4*)(src + 4);
        T[r][c + 0] = (bf16_t)(v0.x * scale); T[r][c + 1] = (bf16_t)(v0.y * scale);
        T[r][c + 2] = (bf16_t)(v0.z * scale); T[r][c + 3] = (bf16_t)(v0.w * scale);
        T[r][c + 4] = (bf16_t)(v1.x * scale); T[r][c + 5] = (bf16_t)(v1.y * scale);
        T[r][c + 6] = (bf16_t)(v1.z * scale); T[r][c + 7] = (bf16_t)(v1.w * scale);
    }
    __syncthreads();
#pragma unroll
    for (int p = 0; p < 2; p++) {
        int rn = (tid >> 3) + p * 32;      // n
        int ck = (tid & 7) * 8;            // k
        bf16x8 v;
#pragma unroll
        for (int i = 0; i < 8; i++) v[i] = T[ck + i][rn];
        *(bf16x8*)(Wt + (size_t)(n0 + rn) * K + k0 + ck) = v;
    }
}

// One LN row per wave: shuffle-only reduction, no barriers, no LDS.
__device__ __forceinline__ void ln_row_wave(const float* in, const float* g,
                                            const float* bt, bf16_t* out, int row) {
    const int lane = threadIdx.x & 63;
    const float4* src = (const float4*)(in + (size_t)row * 1024);
    float4 xv[4];
    float s = 0.f, ss = 0.f;
#pragma unroll
    for (int k = 0; k < 4; k++) {
        xv[k] = src[lane + k * 64];
        s  += xv[k].x + xv[k].y + xv[k].z + xv[k].w;
        ss += xv[k].x * xv[k].x + xv[k].y * xv[k].y + xv[k].z * xv[k].z + xv[k].w * xv[k].w;
    }
#pragma unroll
    for (int off = 32; off > 0; off >>= 1) {
        s  += __shfl_down(s, off);
        ss += __shfl_down(ss, off);
    }
    s  = __shfl(s, 0);
    ss = __shfl(ss, 0);
    const float mu = s * (1.f / 1024.f);
    const float var = ss * (1.f / 1024.f) - mu * mu;
    const float rs = rsqrtf(var + 1e-5f);
    const float4* gp = (const float4*)g;
    const float4* bp = (const float4*)bt;
#pragma unroll
    for (int k = 0; k < 4; k++) {
        float4 gv = gp[lane + k * 64], bv = bp[lane + k * 64];
        bf16x4 o;
        o[0] = (bf16_t)((xv[k].x - mu) * rs * gv.x + bv.x);
        o[1] = (bf16_t)((xv[k].y - mu) * rs * gv.y + bv.y);
        o[2] = (bf16_t)((xv[k].z - mu) * rs * gv.z + bv.z);
        o[3] = (bf16_t)((xv[k].w - mu) * rs * gv.w + bv.w);
        *(bf16x4*)(out + (size_t)row * 1024 + (lane + k * 64) * 4) = o;
    }
}

__global__ __launch_bounds__(256) void prep_kernel(const float* __restrict__ x,
                                                   const float* __restrict__ ctx,
                                                   const float* __restrict__ g1,
                                                   const float* __restrict__ b1,
                                                   const float* __restrict__ g2,
                                                   const float* __restrict__ b2,
                                                   const float* __restrict__ Wq,
                                                   const float* __restrict__ Wkv,
                                                   const float* __restrict__ Wout,
                                                   bf16_t* __restrict__ xn,
                                                   bf16_t* __restrict__ cn,
                                                   bf16_t* __restrict__ Wqt,
                                                   bf16_t* __restrict__ Wkvt,
                                                   bf16_t* __restrict__ Woutt) {
    int id = blockIdx.x;
    if (id < 128) {
        wtrans_tile(Wq, Wqt, 1024, 512, (id & 7) * 64, (id >> 3) * 64, QSCALE);
    } else if (id < 384) {
        int t = id - 128;
        wtrans_tile(Wkv, Wkvt, 1024, 1024, (t & 15) * 64, (t >> 4) * 64, 1.0f);
    } else if (id < 512) {
        int t = id - 384;
        wtrans_tile(Wout, Woutt, 512, 1024, (t & 15) * 64, (t >> 4) * 64, 1.0f);
    } else {
        int row = (id - 512) * 4 + (threadIdx.x >> 6);   // one row per wave
        if (row < BATCH * SEQ_N) ln_row_wave(x, g1, b1, xn, row);
        else                     ln_row_wave(ctx, g2, b2, cn, row - BATCH * SEQ_N);
    }
}

// ---------------- m97-style GEMM body; NT = col-tile width (128 or 64) ------
// R10: (a) LDS passed in by the kernel (one allocation shared by all template
// instantiations -- the old per-instantiation static __shared__ doubled the
// qkv kernel to 64KB and halved occupancy); (b) T2 XOR-swizzle via the attn-
// proven pattern: glds keeps a LINEAR dest, the GLOBAL source col-chunk is
// pre-swizzled (a -> a^(row&7)), fragment reads XOR with (l16&7)<<3. Kills
// the 9.6e6-cycle 16-way bank conflict on row-stride-128B reads.
// MODE 0: C[row*ldC + col] (+bias). MODE 1 (NT=128): transposed output (V^T).
template <int NT, int MODE, typename OutT>
__device__ __forceinline__ void gemm_body(const bf16_t* __restrict__ A,
                                          const bf16_t* __restrict__ Bt,
                                          OutT* __restrict__ C,
                                          const float* __restrict__ bias,
                                          int ldC, int K, int row0, int col0,
                                          bf16_t* As, bf16_t* Bs) {
    const int tid = threadIdx.x;
    const int wave = tid >> 6, lane = tid & 63;
    constexpr int WC = NT / 2;      // wave col extent
    constexpr int NJ = WC / 16;     // 4 or 2
    const int wr = (wave >> 1) * 64, wc = (wave & 1) * WC;
    const int quad = lane >> 4, l16 = lane & 15;
    const int swz = (l16 & 7) << 3;          // read-side XOR (row&7 == l16&7)

    floatx4 acc[4][NJ] = {};

    for (int k0 = 0; k0 < K; k0 += 64) {
#pragma unroll
        for (int p = 0; p < 4; p++) {
            int cA = p * 256 + wave * 64 + lane;
            int rA = cA >> 3;
            int kc = ((cA & 7) ^ (rA & 7)) * 8;   // pre-swizzled source col
            __builtin_amdgcn_global_load_lds(
                (gptr_t)(A + (size_t)(row0 + rA) * K + k0 + kc),
                (lptr_t)(As + (size_t)(p * 256 + wave * 64) * 8), 16, 0, 0);
            if (p < NT / 32)
                __builtin_amdgcn_global_load_lds(
                    (gptr_t)(Bt + (size_t)(col0 + rA) * K + k0 + kc),
                    (lptr_t)(Bs + (size_t)(p * 256 + wave * 64) * 8), 16, 0, 0);
        }
        __syncthreads();
#pragma unroll
        for (int kt = 0; kt < 2; kt++) {
            bf16x8 aF[4], bF[NJ];
            int rc = (kt * 32 + quad * 8) ^ swz;
#pragma unroll
            for (int i = 0; i < 4; i++)
                aF[i] = *(bf16x8*)&As[(wr + i * 16 + l16) * 64 + rc];
#pragma unroll
            for (int j = 0; j < NJ; j++)
                bF[j] = *(bf16x8*)&Bs[(wc + j * 16 + l16) * 64 + rc];
#pragma unroll
            for (int i = 0; i < 4; i++)
#pragma unroll
                for (int j = 0; j < NJ; j++) {
                    if (MODE == 0)
                        acc[i][j] = __builtin_amdgcn_mfma_f32_16x16x32_bf16(
                            aF[i], bF[j], acc[i][j], 0, 0, 0);
                    else  // transposed output: D^T
                        acc[i][j] = __builtin_amdgcn_mfma_f32_16x16x32_bf16(
                            bF[j], aF[i], acc[i][j], 0, 0, 0);
                }
        }
        __syncthreads();
    }

    if (MODE == 0) {
#pragma unroll
        for (int i = 0; i < 4; i++)
#pragma unroll
            for (int j = 0; j < NJ; j++) {
                int col = col0 + wc + j * 16 + l16;
                float bv = bias ? bias[col] : 0.f;
#pragma unroll
                for (int r = 0; r < 4; r++) {
                    int row = row0 + wr + i * 16 + quad * 4 + r;
                    C[(size_t)row * ldC + col] = (OutT)(acc[i][j][r] + bv);
                }
            }
    } else {
        // lane holds D^T[d_local = j*16+quad*4+r][m_local = i*16+l16] for wave
        // tile (64 m x 64 d). Transpose via per-wave LDS chunk, then vector-store.
        bf16_t* Tw = (wave < 2 ? As : Bs) + (wave & 1) * 4096;  // 64x64, stride 64
#pragma unroll
        for (int i = 0; i < 4; i++)
#pragma unroll
            for (int j = 0; j < 4; j++)
#pragma unroll
                for (int r = 0; r < 4; r++)
                    Tw[(j * 16 + quad * 4 + r) * 64 + i * 16 + l16] = (bf16_t)acc[i][j][r];
        __syncthreads();
        const int grow = row0 + wr;                  // wave m base (64 aligned)
        const int bat = grow >> 11, gm = (grow & 2047) + l16 * 4;
#pragma unroll
        for (int dd = 0; dd < 16; dd++) {
            int d = dd * 4 + quad;
            bf16x4 v = *(bf16x4*)&Tw[d * 64 + l16 * 4];
            int gd = col0 + wc + d - 512;
            *(bf16x4*)(C + ((size_t)bat * 512 + gd) * 2048 + gm) = v;
        }
    }
}

// Fused q/k/v projections, XCD-chunked 1D grid (768 blocks, 768%8==0):
// each XCD owns 8 consecutive 128-row panels (all 12 col-tiles) -> A-panels
// read once per XCD, weights (<=3MB) stay L2-resident. ONE 32KB LDS pair
// shared by all gemm_body instantiations (was 64KB -> 2 blocks/CU).
__global__ __launch_bounds__(256) void gemm_qkv_kernel(const bf16_t* __restrict__ xn,
                                                       const bf16_t* __restrict__ cn,
                                                       const bf16_t* __restrict__ Wqt,
                                                       const bf16_t* __restrict__ Wkvt,
                                                       bf16_t* __restrict__ qb,
                                                       bf16_t* __restrict__ kvb,
                                                       bf16_t* __restrict__ Vtg) {
    __shared__ bf16_t As[128 * 64];
    __shared__ bf16_t Bs[128 * 64];
    const int f = blockIdx.x;
    const int lb = (f & 7) * 96 + (f >> 3);
    const int bx = lb % 12;
    const int row0 = (lb / 12) * 128;
    if (bx < 4)
        gemm_body<128, 0, bf16_t>(xn, Wqt, qb, nullptr, 512, DIM, row0, bx * 128, As, Bs);
    else if (bx < 8)
        gemm_body<128, 0, bf16_t>(cn, Wkvt, kvb, nullptr, 512, DIM, row0, (bx - 4) * 128, As, Bs);
    else
        gemm_body<128, 1, bf16_t>(cn, Wkvt, Vtg, nullptr, 0, DIM, row0, (bx - 4) * 128, As, Bs);
}

// XCD-chunked 1D grid (1024 blocks): each XCD owns 8 row-panels of ao.
__global__ __launch_bounds__(256) void gemm_out_kernel(const bf16_t* __restrict__ ao,
                                                       const bf16_t* __restrict__ Woutt,
                                                       float* __restrict__ out,
                                                       const float* __restrict__ bias) {
    __shared__ bf16_t As[128 * 64];
    __shared__ bf16_t Bs[64 * 64];
    const int f = blockIdx.x;
    const int lb = (f & 7) * 128 + (f >> 3);
    gemm_body<64, 0, float>(ao, Woutt, out, bias, DIM, INNER,
                            (lb >> 4) * 128, (lb & 15) * 64, As, Bs);
}

// ---------------- Flash attention v9 (R9-verified, ~49us): 256 threads,
// 32 q-rows/wave, glds K/V triple-buffer, cross-iteration software pipeline
// [exp/pack P(it); QK(it+1); PV(it)], XOR-swizzled LDS, raw exp2, setprio.
// q: [b,n,512]; kv: [b,m,512] K-only; Vtg: [(b*8+h)*64+d][m]. o: [b,n,512].
__global__ __launch_bounds__(256, 2) void attn_kernel(const bf16_t* __restrict__ q,
                                                      const bf16_t* __restrict__ kv,
                                                      const bf16_t* __restrict__ Vtg,
                                                      bf16_t* __restrict__ o) {
    __shared__ bf16_t Qs[128 * 64];      // Q staging; later per-wave P buffers
    __shared__ bf16_t Ks[3][64 * 64];    // [krow][d] XOR layout, triple-buffered
    __shared__ bf16_t Vs[3][64 * 64];    // [d][krow] XOR layout, triple-buffered

    // XCD-chunked block swizzle: 512 blocks, 64 consecutive logical per XCD
    // = 4 (b,h) pairs (~2MB KV per XCD L2).
    const int f = blockIdx.x;
    const int lb = ((f & 7) << 6) | (f >> 3);
    const int b = lb >> 7, h = (lb >> 4) & 7;
    const int n0 = (lb & 15) * 128;

    const int tid = threadIdx.x;
    const int wave = tid >> 6, lane = tid & 63;
    const int quad = lane >> 4, l16 = lane & 15;
    const int swz = (l16 & 7) << 3;          // read-side XOR (row&7 == l16&7)

    const int sr = tid >> 3;                 // Q staging row base (0..31)
    const int sc = (tid & 7) * 8;            // Q staging col
    const int scs = sc ^ ((sr & 7) << 3);    // write-side XOR (row&7 == sr&7)

    // glds staging: wave w owns chunks 2w, 2w+1 (rows 16w..16w+15); lane covers
    // row rloc=(lane>>3) of an 8-row chunk, 16B col chunk (lane&7); source col
    // pre-swizzled so linear LDS dest == XOR layout.
    const int rloc = lane >> 3;                        // 0..7
    const int srccol = ((lane & 7) ^ rloc) << 3;       // (a ^ r)*8 elems
    const bf16_t* kgl = kv + ((size_t)(b * SEQ_M) + wave * 16 + rloc) * 512
                           + h * DHEAD + srccol;
    const bf16_t* vgl = Vtg + ((size_t)((b * HEADS + h) * DHEAD)
                               + wave * 16 + rloc) * SEQ_M + srccol;

    // stage one 64-row K/V tile into (KD,VD), advance source to next tile
    auto STAGE = [&](bf16_t* KD, bf16_t* VD) {
#pragma unroll
        for (int p = 0; p < 2; p++) {
            __builtin_amdgcn_global_load_lds(
                (gptr_t)(kgl + (size_t)(p * 8) * 512),
                (lptr_t)(KD + (wave * 2 + p) * 512), 16, 0, 0);
            __builtin_amdgcn_global_load_lds(
                (gptr_t)(vgl + (size_t)(p * 8) * SEQ_M),
                (lptr_t)(VD + (wave * 2 + p) * 512), 16, 0, 0);
        }
        kgl += (size_t)64 * 512;
        vgl += 64;
    };

    STAGE(Ks[0], Vs[0]);     // tile 0
    STAGE(Ks[1], Vs[1]);     // tile 1 (both drained at the first barrier)

    // stage Q tile [128][64] (swizzled, reg path)
#pragma unroll
    for (int p = 0; p < 4; p++) {
        int r = sr + p * 32;
        *(bf16x8*)&Qs[r * 64 + scs] =
            *(const bf16x8*)(q + (size_t)(b * SEQ_N + n0 + r) * INNER + h * DHEAD + sc);
    }

    // ones B-frag for the l-column MFMA: B[k][n=l16] = (l16==0) ? 1 : 0
    bf16x8 bOnes;
    {
        bf16_t ov = (l16 == 0) ? (bf16_t)1.0f : (bf16_t)0.0f;
#pragma unroll
        for (int i = 0; i < 8; i++) bOnes[i] = ov;
    }

    __syncthreads();     // Q visible; tiles 0,1 drained

    // per-wave Q fragments: 2 sets of 16 q-rows (rows wave*32 .. wave*32+31)
    bf16x8 aQ0[2], aQ1[2];
#pragma unroll
    for (int kt = 0; kt < 2; kt++) {
        aQ0[kt] = *(bf16x8*)&Qs[(wave * 32 + l16) * 64 + ((kt * 32 + quad * 8) ^ swz)];
        aQ1[kt] = *(bf16x8*)&Qs[(wave * 32 + 16 + l16) * 64 + ((kt * 32 + quad * 8) ^ swz)];
    }

    STAGE(Ks[2], Vs[2]);     // tile 2 in flight during iter 0

    // S^T = K @ Q^T (exp2 domain): aK read once, feeds BOTH q-sets
    auto QK = [&](const bf16_t* KB, floatx4* d0, floatx4* d1) {
#pragma unroll
        for (int kt = 0; kt < 2; kt++)
#pragma unroll
            for (int jt = 0; jt < 4; jt++) {
                bf16x8 aK = *(bf16x8*)&KB[(jt * 16 + l16) * 64 +
                                          ((kt * 32 + quad * 8) ^ swz)];
                d0[jt] = __builtin_amdgcn_mfma_f32_16x16x32_bf16(aK, aQ0[kt], d0[jt], 0, 0, 0);
                d1[jt] = __builtin_amdgcn_mfma_f32_16x16x32_bf16(aK, aQ1[kt], d1[jt], 0, 0, 0);
            }
    };

    // per-wave P buffers alias this wave's (already-consumed) Qs rows
    bf16_t* Pw0 = Qs + wave * 2048;          // set 0: rows wave*32..+15
    bf16_t* Pw1 = Pw0 + 1024;                // set 1: rows wave*32+16..+31

    floatx4 oacc0[5] = {}, oacc1[5] = {};    // [0..3]=O d-tiles, [4]=l (col 0)

    // rotating buffer roles: c=tile it (PV), n=tile it+1 (QK), x=in-flight
    bf16_t *cK = Ks[0], *cV = Vs[0];
    bf16_t *nK = Ks[1], *nV = Vs[1];
    bf16_t *xK = Ks[2], *xV = Vs[2];

    // prologue: S(0) from tile 0
    floatx4 s0[4] = {}, s1[4] = {};
    QK(cK, s0, s1);

    for (int it = 0; it < SEQ_M / 64; ++it) {
        // P(it) = exp2(S(it)): packed b64 stores at P[q=l16][m=jt*16+quad*4]
#pragma unroll
        for (int jt = 0; jt < 4; jt++) {
            bf16x4 pk0, pk1;
#pragma unroll
            for (int r = 0; r < 4; r++) {
                pk0[r] = (bf16_t)fast_exp2(s0[jt][r]);
                pk1[r] = (bf16_t)fast_exp2(s1[jt][r]);
            }
            int pc = (jt * 16 + quad * 4) ^ swz;
            *(bf16x4*)&Pw0[l16 * 64 + pc] = pk0;
            *(bf16x4*)&Pw1[l16 * 64 + pc] = pk1;
        }

        __builtin_amdgcn_s_setprio(1);
        // QK(it+1) from nK — independent of exp above: compiler interleaves
        floatx4 t0[4] = {}, t1[4] = {};
        QK(nK, t0, t1);

        // PV(it): O += P(it) @ V(it); l via register ones-frag
#pragma unroll
        for (int kt = 0; kt < 2; kt++) {
            int ac = (kt * 32 + quad * 8) ^ swz;
            bf16x8 aP0 = *(bf16x8*)&Pw0[l16 * 64 + ac];
            bf16x8 aP1 = *(bf16x8*)&Pw1[l16 * 64 + ac];
#pragma unroll
            for (int dt = 0; dt < 4; dt++) {
                bf16x8 bV = *(bf16x8*)&cV[(dt * 16 + l16) * 64 + ac];
                oacc0[dt] = __builtin_amdgcn_mfma_f32_16x16x32_bf16(aP0, bV, oacc0[dt], 0, 0, 0);
                oacc1[dt] = __builtin_amdgcn_mfma_f32_16x16x32_bf16(aP1, bV, oacc1[dt], 0, 0, 0);
            }
            oacc0[4] = __builtin_amdgcn_mfma_f32_16x16x32_bf16(aP0, bOnes, oacc0[4], 0, 0, 0);
            oacc1[4] = __builtin_amdgcn_mfma_f32_16x16x32_bf16(aP1, bOnes, oacc1[4], 0, 0, 0);
        }
        __builtin_amdgcn_s_setprio(0);

        __syncthreads();     // all waves: PV(it) done (cV free), glds(it+2) drained

        // refill the just-freed buffer with tile it+3 (in flight a full iter;
        // OOB tail reads land in adjacent ws regions, unused)
        STAGE(cK, cV);

        // rotate roles and carry S(it+1)
        bf16_t* t;
        t = cK; cK = nK; nK = xK; xK = t;
        t = cV; cV = nV; nV = xV; xV = t;
#pragma unroll
        for (int jt = 0; jt < 4; jt++) { s0[jt] = t0[jt]; s1[jt] = t1[jt]; }
    }

    // epilogue: l in oacc*[4] col 0; broadcast within quad-row group
#pragma unroll
    for (int set = 0; set < 2; set++) {
        const floatx4* oa = set == 0 ? oacc0 : oacc1;   // compile-time select
        float inv[4];
#pragma unroll
        for (int r = 0; r < 4; r++) {
            float l = __shfl(oa[4][r], (int)(lane & 48));
            inv[r] = 1.0f / l;
        }
#pragma unroll
        for (int dt = 0; dt < 4; dt++)
#pragma unroll
            for (int r = 0; r < 4; r++) {
                int row = n0 + wave * 32 + set * 16 + quad * 4 + r;
                int col = h * DHEAD + dt * 16 + l16;
                o[(size_t)(b * SEQ_N + row) * INNER + col] =
                    (bf16_t)(oa[dt][r] * inv[r]);
            }
    }
}

extern "C" void kernel_launch(void* const* d_in, const int* in_sizes, int n_in,
                              void* d_out, int out_size, void* d_ws, size_t ws_size,
                              hipStream_t stream) {
    const float* x    = (const float*)d_in[0];
    const float* ctx  = (const float*)d_in[1];
    const float* g1   = (const float*)d_in[2];
    const float* b1   = (const float*)d_in[3];
    const float* g2   = (const float*)d_in[4];
    const float* b2   = (const float*)d_in[5];
    const float* Wq   = (const float*)d_in[6];
    const float* Wkv  = (const float*)d_in[7];
    const float* Wout = (const float*)d_in[8];
    const float* bout = (const float*)d_in[9];
    float* out = (float*)d_out;

    const int rows = BATCH * SEQ_N;  // 8192
    bf16_t* xn    = (bf16_t*)d_ws;                       // 8M elem; reused as attn out
    bf16_t* cn    = xn + (size_t)rows * DIM;             // 8M
    bf16_t* qb    = cn + (size_t)rows * DIM;             // 4M
    bf16_t* kvb   = qb + (size_t)rows * INNER;           // 4M (K only, stride 512)
    bf16_t* Vtg   = kvb + (size_t)rows * INNER;          // 4M (V transposed)
    bf16_t* Wqt   = Vtg + (size_t)rows * INNER;          // 0.5M
    bf16_t* Wkvt  = Wqt + (size_t)INNER * DIM;           // 1M
    bf16_t* Woutt = Wkvt + (size_t)(2 * INNER) * DIM;    // 0.5M
    bf16_t* o_attn = xn;  // alias: xn dead after qkv GEMM

    prep_kernel<<<512 + (2 * rows) / 4, 256, 0, stream>>>(
        x, ctx, g1, b1, g2, b2, Wq, Wkv, Wout, xn, cn, Wqt, Wkvt, Woutt);
    gemm_qkv_kernel<<<768, 256, 0, stream>>>(
        xn, cn, Wqt, Wkvt, qb, kvb, Vtg);
    attn_kernel<<<512, 256, 0, stream>>>(qb, kvb, Vtg, o_attn);
    gemm_out_kernel<<<1024, 256, 0, stream>>>(o_attn, Woutt, out, bout);
}